// Round 1
// baseline (1564.352 us; speedup 1.0000x reference)
//
#include <hip/hip_runtime.h>

#define BROWS 65536
#define EPS_BN 1e-5f
#define NSTD 0.1f

struct NodeA {
  const float* inA;   // cols 0..127 of input, row stride ldA
  const float* inB;   // cols 128..255 of input, row stride ldB
  int ldA, ldB;
  const float* W1;    // [256][256]
  const float* b1;    // [256]
  const float* W2;    // [256][128]
  const float* b2;    // [128]
  float* y;           // [B][128] pre-BN output
  float* sum;         // [128] col sums (atomic)
  float* sumsq;       // [128] col sums of squares (atomic)
};

struct NodeC {
  const float* y; float* out;
  const float* sum; const float* sumsq;
  const float* gamma; const float* beta;
  const float* noise;  // nullptr for nodes 0,1
};

__global__ void zero_f32(float* p, int n) {
  int i = blockIdx.x * blockDim.x + threadIdx.x;
  if (i < n) p[i] = 0.0f;
}

// Fused: y = (relu(x@W1+b1))@W2 + b2, plus per-column sum/sumsq accumulation.
// Block: 256 threads, 64 rows. GEMM1 micro-tile 8x8, GEMM2 micro-tile 8x4.
__global__ __launch_bounds__(256) void mlp_node(NodeA nd0, NodeA nd1) {
  const NodeA nd = (blockIdx.y == 0) ? nd0 : nd1;
  __shared__ float xs[64 * 256];   // 64 KB: x tile, then h tile
  __shared__ float ws[16 * 256];   // 16 KB: weight panels, then reduction buf

  const int tid = threadIdx.x;
  const int m0 = blockIdx.x * 64;
  const int tr = tid >> 5;   // 0..7  (row group)
  const int tc = tid & 31;   // 0..31 (col group)

  // ---- load x tile (64 x 256) : cols 0-127 from inA, 128-255 from inB ----
  #pragma unroll
  for (int i = 0; i < 16; ++i) {
    int f = tid + i * 256;          // float4 index, 4096 total
    int row = f >> 6;
    int c4 = f & 63;
    float4 v;
    if (c4 < 32) v = *(const float4*)(nd.inA + (size_t)(m0 + row) * nd.ldA + c4 * 4);
    else         v = *(const float4*)(nd.inB + (size_t)(m0 + row) * nd.ldB + (c4 - 32) * 4);
    *(float4*)(xs + f * 4) = v;
  }

  // ---- GEMM1: h(64x256) = relu(x @ W1 + b1) ----
  float acc1[8][8];
  #pragma unroll
  for (int r = 0; r < 8; ++r)
    #pragma unroll
    for (int c = 0; c < 8; ++c) acc1[r][c] = 0.f;

  for (int kt = 0; kt < 256; kt += 16) {
    __syncthreads();
    #pragma unroll
    for (int i = 0; i < 4; ++i) {
      int f = tid + i * 256;        // 1024 float4 = 16x256 panel
      int kr = f >> 6, c4 = f & 63;
      *(float4*)(ws + f * 4) = *(const float4*)(nd.W1 + (size_t)(kt + kr) * 256 + c4 * 4);
    }
    __syncthreads();
    #pragma unroll
    for (int k4 = 0; k4 < 16; k4 += 4) {
      float4 af[8];
      #pragma unroll
      for (int r = 0; r < 8; ++r)
        af[r] = *(const float4*)(xs + (tr * 8 + r) * 256 + kt + k4);
      #pragma unroll
      for (int kk = 0; kk < 4; ++kk) {
        float4 bv0 = *(const float4*)(ws + (k4 + kk) * 256 + tc * 8);
        float4 bv1 = *(const float4*)(ws + (k4 + kk) * 256 + tc * 8 + 4);
        float bb[8] = {bv0.x, bv0.y, bv0.z, bv0.w, bv1.x, bv1.y, bv1.z, bv1.w};
        #pragma unroll
        for (int r = 0; r < 8; ++r) {
          float av = (kk == 0) ? af[r].x : (kk == 1) ? af[r].y : (kk == 2) ? af[r].z : af[r].w;
          #pragma unroll
          for (int c = 0; c < 8; ++c)
            acc1[r][c] = fmaf(av, bb[c], acc1[r][c]);
        }
      }
    }
  }

  // bias + relu, h -> xs (reuse)
  __syncthreads();
  {
    float4 blo = *(const float4*)(nd.b1 + tc * 8);
    float4 bhi = *(const float4*)(nd.b1 + tc * 8 + 4);
    float bb[8] = {blo.x, blo.y, blo.z, blo.w, bhi.x, bhi.y, bhi.z, bhi.w};
    #pragma unroll
    for (int r = 0; r < 8; ++r) {
      float4 h0, h1;
      h0.x = fmaxf(acc1[r][0] + bb[0], 0.f); h0.y = fmaxf(acc1[r][1] + bb[1], 0.f);
      h0.z = fmaxf(acc1[r][2] + bb[2], 0.f); h0.w = fmaxf(acc1[r][3] + bb[3], 0.f);
      h1.x = fmaxf(acc1[r][4] + bb[4], 0.f); h1.y = fmaxf(acc1[r][5] + bb[5], 0.f);
      h1.z = fmaxf(acc1[r][6] + bb[6], 0.f); h1.w = fmaxf(acc1[r][7] + bb[7], 0.f);
      *(float4*)(xs + (tr * 8 + r) * 256 + tc * 8) = h0;
      *(float4*)(xs + (tr * 8 + r) * 256 + tc * 8 + 4) = h1;
    }
  }
  __syncthreads();

  // ---- GEMM2: y(64x128) = h @ W2 + b2 ----
  float acc2[8][4];
  #pragma unroll
  for (int r = 0; r < 8; ++r)
    #pragma unroll
    for (int c = 0; c < 4; ++c) acc2[r][c] = 0.f;

  for (int kt = 0; kt < 256; kt += 16) {
    __syncthreads();
    #pragma unroll
    for (int i = 0; i < 2; ++i) {
      int f = tid + i * 256;        // 512 float4 = 16x128 panel
      int kr = f >> 5, c4 = f & 31;
      *(float4*)(ws + f * 4) = *(const float4*)(nd.W2 + (size_t)(kt + kr) * 128 + c4 * 4);
    }
    __syncthreads();
    #pragma unroll
    for (int k4 = 0; k4 < 16; k4 += 4) {
      float4 af[8];
      #pragma unroll
      for (int r = 0; r < 8; ++r)
        af[r] = *(const float4*)(xs + (tr * 8 + r) * 256 + kt + k4);
      #pragma unroll
      for (int kk = 0; kk < 4; ++kk) {
        float4 bv = *(const float4*)(ws + (k4 + kk) * 128 + tc * 4);
        #pragma unroll
        for (int r = 0; r < 8; ++r) {
          float av = (kk == 0) ? af[r].x : (kk == 1) ? af[r].y : (kk == 2) ? af[r].z : af[r].w;
          acc2[r][0] = fmaf(av, bv.x, acc2[r][0]);
          acc2[r][1] = fmaf(av, bv.y, acc2[r][1]);
          acc2[r][2] = fmaf(av, bv.z, acc2[r][2]);
          acc2[r][3] = fmaf(av, bv.w, acc2[r][3]);
        }
      }
    }
  }

  // ---- epilogue: +b2, store y, accumulate column sums/sumsq ----
  __syncthreads();                       // done reading ws; reuse as reduce buf
  float* lsum = ws;
  float* lsq  = ws + 128;
  if (tid < 128) { lsum[tid] = 0.f; lsq[tid] = 0.f; }
  __syncthreads();

  float4 b2v = *(const float4*)(nd.b2 + tc * 4);
  float cs[4] = {0.f, 0.f, 0.f, 0.f};
  float cq[4] = {0.f, 0.f, 0.f, 0.f};
  #pragma unroll
  for (int r = 0; r < 8; ++r) {
    float4 yv;
    yv.x = acc2[r][0] + b2v.x;
    yv.y = acc2[r][1] + b2v.y;
    yv.z = acc2[r][2] + b2v.z;
    yv.w = acc2[r][3] + b2v.w;
    *(float4*)(nd.y + (size_t)(m0 + tr * 8 + r) * 128 + tc * 4) = yv;
    cs[0] += yv.x; cq[0] += yv.x * yv.x;
    cs[1] += yv.y; cq[1] += yv.y * yv.y;
    cs[2] += yv.z; cq[2] += yv.z * yv.z;
    cs[3] += yv.w; cq[3] += yv.w * yv.w;
  }
  #pragma unroll
  for (int c = 0; c < 4; ++c) {
    atomicAdd(&lsum[tc * 4 + c], cs[c]);
    atomicAdd(&lsq[tc * 4 + c],  cq[c]);
  }
  __syncthreads();
  if (tid < 128)      atomicAdd(&nd.sum[tid],         lsum[tid]);
  else                atomicAdd(&nd.sumsq[tid - 128], lsq[tid - 128]);
}

// BN normalize (in place) + optional noise. One thread = one float4 (4 cols).
__global__ __launch_bounds__(256) void bn_apply(NodeC c0, NodeC c1) {
  const NodeC c = (blockIdx.y == 0) ? c0 : c1;
  const size_t e = (size_t)blockIdx.x * blockDim.x + threadIdx.x;  // float4 idx
  const int col4 = ((int)e & 31) * 4;
  const float invB = 1.0f / 65536.0f;

  float4 s = *(const float4*)(c.sum + col4);
  float4 q = *(const float4*)(c.sumsq + col4);
  float mu0 = s.x * invB, mu1 = s.y * invB, mu2 = s.z * invB, mu3 = s.w * invB;
  float rs0 = rsqrtf(q.x * invB - mu0 * mu0 + EPS_BN);
  float rs1 = rsqrtf(q.y * invB - mu1 * mu1 + EPS_BN);
  float rs2 = rsqrtf(q.z * invB - mu2 * mu2 + EPS_BN);
  float rs3 = rsqrtf(q.w * invB - mu3 * mu3 + EPS_BN);

  float4 g  = *(const float4*)(c.gamma + col4);
  float4 bt = *(const float4*)(c.beta + col4);
  float4 yv = *(const float4*)(c.y + e * 4);

  float4 o;
  o.x = g.x * (yv.x - mu0) * rs0 + bt.x;
  o.y = g.y * (yv.y - mu1) * rs1 + bt.y;
  o.z = g.z * (yv.z - mu2) * rs2 + bt.z;
  o.w = g.w * (yv.w - mu3) * rs3 + bt.w;
  if (c.noise) {
    float4 nz = *(const float4*)(c.noise + e * 4);
    o.x += NSTD * nz.x; o.y += NSTD * nz.y; o.z += NSTD * nz.z; o.w += NSTD * nz.w;
  }
  *(float4*)(c.out + e * 4) = o;
}

extern "C" void kernel_launch(void* const* d_in, const int* in_sizes, int n_in,
                              void* d_out, int out_size, void* d_ws, size_t ws_size,
                              hipStream_t stream) {
  const float* x1    = (const float*)d_in[0];
  const float* x2    = (const float*)d_in[1];
  const float* W1    = (const float*)d_in[2];
  const float* b1    = (const float*)d_in[3];
  const float* W2    = (const float*)d_in[4];
  const float* b2    = (const float*)d_in[5];
  const float* gamma = (const float*)d_in[6];
  const float* beta  = (const float*)d_in[7];
  const float* noise = (const float*)d_in[8];
  float* out = (float*)d_out;

  const size_t S = (size_t)BROWS * 128;
  float* o3 = out;
  float* o4 = out + S;
  float* o0 = out + 2 * S;
  float* o1 = out + 3 * S;
  float* o2 = out + 4 * S;

  float* stats = (float*)d_ws;   // 5 nodes x (sum[128], sumsq[128])

  auto mkA = [&](int i, const float* pA, int ldA, const float* pB, int ldB, float* y) {
    NodeA n;
    n.inA = pA; n.inB = pB; n.ldA = ldA; n.ldB = ldB;
    n.W1 = W1 + (size_t)i * 256 * 256;
    n.b1 = b1 + (size_t)i * 256;
    n.W2 = W2 + (size_t)i * 256 * 128;
    n.b2 = b2 + (size_t)i * 128;
    n.y = y;
    n.sum = stats + i * 256;
    n.sumsq = stats + i * 256 + 128;
    return n;
  };
  auto mkC = [&](int i, float* y, const float* nz) {
    NodeC c;
    c.y = y; c.out = y;
    c.sum = stats + i * 256;
    c.sumsq = stats + i * 256 + 128;
    c.gamma = gamma + (size_t)i * 128;
    c.beta  = beta + (size_t)i * 128;
    c.noise = nz;
    return c;
  };

  dim3 blk(256);

  // zero the stats accumulators (ws is re-poisoned before every call)
  zero_f32<<<dim3(5), blk, 0, stream>>>(stats, 5 * 256);

  // nodes 0,1 (inputs x1,x2)
  NodeA a0 = mkA(0, x1, 256, x1 + 128, 256, o0);
  NodeA a1 = mkA(1, x2, 256, x2 + 128, 256, o1);
  mlp_node<<<dim3(BROWS / 64, 2), blk, 0, stream>>>(a0, a1);
  NodeC c0 = mkC(0, o0, nullptr);
  NodeC c1 = mkC(1, o1, nullptr);
  bn_apply<<<dim3(S / 4 / 256, 2), blk, 0, stream>>>(c0, c1);

  // node 2 (concat(o0,o1)) + noise[0]
  NodeA a2 = mkA(2, o0, 128, o1, 128, o2);
  mlp_node<<<dim3(BROWS / 64, 1), blk, 0, stream>>>(a2, a2);
  NodeC c2 = mkC(2, o2, noise);
  bn_apply<<<dim3(S / 4 / 256, 1), blk, 0, stream>>>(c2, c2);

  // nodes 3 (concat(o0,o2)) + noise[1], 4 (concat(o1,o2)) + noise[2]
  NodeA a3 = mkA(3, o0, 128, o2, 128, o3);
  NodeA a4 = mkA(4, o1, 128, o2, 128, o4);
  mlp_node<<<dim3(BROWS / 64, 2), blk, 0, stream>>>(a3, a4);
  NodeC c3 = mkC(3, o3, noise + S);
  NodeC c4 = mkC(4, o4, noise + 2 * S);
  bn_apply<<<dim3(S / 4 / 256, 2), blk, 0, stream>>>(c3, c4);
}

// Round 5
// 964.137 us; speedup vs baseline: 1.6225x; 1.6225x over previous
//
#include <hip/hip_runtime.h>

typedef short bf16x8 __attribute__((ext_vector_type(8)));
typedef float f32x4 __attribute__((ext_vector_type(4)));

#define BROWS 65536
#define EPS_BN 1e-5f
#define NSTD 0.1f

// ws layout: [0, 5120)            : 5 nodes x (sum[128], sumsq[128]) fp32 stats
//            [8192, 8192+1.97MB)  : split-bf16 transposed weights, per node:
//              w1t_hi [256][256], w1t_lo [256][256], w2t_hi [128][256], w2t_lo [128][256]
#define WNODE 196608   // shorts per node
#define WOFF  8192     // byte offset of weights in ws

__device__ __forceinline__ void split1(float x, short& hi, short& lo) {
  unsigned u = __float_as_uint(x);
  hi = (short)(u >> 16);
  float hf = __uint_as_float(u & 0xffff0000u);
  float l = x - hf;
  lo = (short)(__float_as_uint(l) >> 16);
}

__global__ void zero_f32(float* p, int n) {
  int i = blockIdx.x * blockDim.x + threadIdx.x;
  if (i < n) p[i] = 0.0f;
}

// Transpose + split weights: W1[k][n] -> w1t_{hi,lo}[n][k], W2[k][n] -> w2t_{hi,lo}[n][k]
__global__ __launch_bounds__(256) void prep_weights(const float* W1, const float* W2, short* wbuf) {
  int u = blockIdx.x * 256 + threadIdx.x;   // 61440 units, 8 k-elems each
  if (u >= 61440) return;
  const float* src;
  short* dsthi;
  int loStride;
  if (u < 40960) {                           // W1: 5 x 256n x 32kc
    int node = u >> 13;
    int rem = u & 8191;
    int kc = rem >> 8;
    int n = rem & 255;
    src = W1 + (size_t)node * 65536 + (size_t)(kc * 8) * 256 + n;
    dsthi = wbuf + (size_t)node * WNODE + n * 256 + kc * 8;
    loStride = 65536;
    bf16x8 h8, l8;
    #pragma unroll
    for (int j = 0; j < 8; ++j) { short hh, ll; split1(src[j * 256], hh, ll); h8[j] = hh; l8[j] = ll; }
    *(bf16x8*)dsthi = h8;
    *(bf16x8*)(dsthi + loStride) = l8;
  } else {                                   // W2: 5 x 128n x 32kc
    int u2 = u - 40960;
    int node = u2 >> 12;
    int rem = u2 & 4095;
    int kc = rem >> 7;
    int n = rem & 127;
    src = W2 + (size_t)node * 32768 + (size_t)(kc * 8) * 128 + n;
    dsthi = wbuf + (size_t)node * WNODE + 131072 + n * 256 + kc * 8;
    loStride = 32768;
    bf16x8 h8, l8;
    #pragma unroll
    for (int j = 0; j < 8; ++j) { short hh, ll; split1(src[j * 128], hh, ll); h8[j] = hh; l8[j] = ll; }
    *(bf16x8*)dsthi = h8;
    *(bf16x8*)(dsthi + loStride) = l8;
  }
}

struct NodeA {
  const float* inA;   // cols 0..127, row stride ldA
  const float* inB;   // cols 128..255, row stride ldB
  int ldA, ldB;
  const short* w1t;   // hi at 0, lo at +65536 (shorts), layout [n][k]
  const short* w2t;   // hi at 0, lo at +32768, layout [n][k]
  const float* b1; const float* b2;
  float* y; float* sum; float* sumsq;
};

struct NodeC {
  const float* y; float* out;
  const float* sum; const float* sumsq;
  const float* gamma; const float* beta;
  const float* noise;
};

// Fused split-bf16 MFMA node: y = relu(x@W1+b1)@W2 + b2, + column sum/sumsq.
// 512 threads (8 waves), tile 64 rows. Wave grid: 2(M) x 4(N).
__global__ __launch_bounds__(512) void mlp_node(NodeA nd0, NodeA nd1) {
  const NodeA nd = (blockIdx.y == 0) ? nd0 : nd1;
  __shared__ short lds[2][64 * 256];   // hi/lo planes, XOR-swizzled rows (64 KB)

  const int tid = threadIdx.x;
  const int lane = tid & 63;
  const int wid = tid >> 6;
  const int l15 = lane & 15;
  const int l4 = lane >> 4;            // 0..3
  const int m0 = blockIdx.x * 64;
  const int mh = wid >> 2;             // 0..1 : 32-row half
  const int nq = wid & 3;              // 0..3

  // ---- stage X (64x256 fp32) -> split bf16 hi/lo planes in LDS ----
  #pragma unroll
  for (int it = 0; it < 4; ++it) {
    int u = tid + it * 512;            // 2048 units of 8 elems
    int row = u >> 5, kc = u & 31;
    const float* src = (kc < 16) ? (nd.inA + (size_t)(m0 + row) * nd.ldA + kc * 8)
                                 : (nd.inB + (size_t)(m0 + row) * nd.ldB + (kc - 16) * 8);
    float4 a = *(const float4*)src;
    float4 b = *(const float4*)(src + 4);
    bf16x8 h8, l8;
    #pragma unroll
    for (int j = 0; j < 8; ++j) {
      float f = (j < 4) ? (&a.x)[j] : (&b.x)[j - 4];
      short hh, ll; split1(f, hh, ll);
      h8[j] = hh; l8[j] = ll;
    }
    int off = row * 512 + ((kc * 16) ^ ((row & 7) << 4));
    *(bf16x8*)((char*)lds[0] + off) = h8;
    *(bf16x8*)((char*)lds[1] + off) = l8;
  }
  __syncthreads();

  // ---- GEMM1: H(64x256) = X @ W1  (3-product split-bf16) ----
  f32x4 acc[2][4] = {};
  const short* __restrict__ w1hi = nd.w1t;
  const short* __restrict__ w1lo = nd.w1t + 65536;
  for (int kt = 0; kt < 8; ++kt) {
    int kb = kt * 32 + l4 * 8;
    bf16x8 ahi[2], alo[2];
    #pragma unroll
    for (int mf = 0; mf < 2; ++mf) {
      int row = mh * 32 + mf * 16 + l15;
      int off = row * 512 + ((kb * 2) ^ ((row & 7) << 4));
      ahi[mf] = *(const bf16x8*)((const char*)lds[0] + off);
      alo[mf] = *(const bf16x8*)((const char*)lds[1] + off);
    }
    bf16x8 bhi[4], blo[4];
    #pragma unroll
    for (int nf = 0; nf < 4; ++nf) {
      int n = nq * 64 + nf * 16 + l15;
      bhi[nf] = *(const bf16x8*)(w1hi + n * 256 + kb);
      blo[nf] = *(const bf16x8*)(w1lo + n * 256 + kb);
    }
    #pragma unroll
    for (int mf = 0; mf < 2; ++mf)
      #pragma unroll
      for (int nf = 0; nf < 4; ++nf) {
        acc[mf][nf] = __builtin_amdgcn_mfma_f32_16x16x32_bf16(ahi[mf], bhi[nf], acc[mf][nf], 0, 0, 0);
        acc[mf][nf] = __builtin_amdgcn_mfma_f32_16x16x32_bf16(ahi[mf], blo[nf], acc[mf][nf], 0, 0, 0);
        acc[mf][nf] = __builtin_amdgcn_mfma_f32_16x16x32_bf16(alo[mf], bhi[nf], acc[mf][nf], 0, 0, 0);
      }
  }
  __syncthreads();   // all waves done reading X planes

  // ---- bias + relu + split -> H planes (overwrite X planes) ----
  #pragma unroll
  for (int nf = 0; nf < 4; ++nf) {
    int col = nq * 64 + nf * 16 + l15;
    float bb = nd.b1[col];
    #pragma unroll
    for (int mf = 0; mf < 2; ++mf) {
      int rowb = mh * 32 + mf * 16 + l4 * 4;
      #pragma unroll
      for (int r = 0; r < 4; ++r) {
        float h = fmaxf(acc[mf][nf][r] + bb, 0.f);
        short hh, ll; split1(h, hh, ll);
        int off = (rowb + r) * 512 + ((col * 2) ^ (((rowb + r) & 7) << 4));
        *(short*)((char*)lds[0] + off) = hh;
        *(short*)((char*)lds[1] + off) = ll;
      }
    }
  }
  __syncthreads();

  // ---- GEMM2: Y(64x128) = H @ W2 ----
  f32x4 acc2[2][2] = {};
  const short* __restrict__ w2hi = nd.w2t;
  const short* __restrict__ w2lo = nd.w2t + 32768;
  for (int kt = 0; kt < 8; ++kt) {
    int kb = kt * 32 + l4 * 8;
    bf16x8 ahi[2], alo[2];
    #pragma unroll
    for (int mf = 0; mf < 2; ++mf) {
      int row = mh * 32 + mf * 16 + l15;
      int off = row * 512 + ((kb * 2) ^ ((row & 7) << 4));
      ahi[mf] = *(const bf16x8*)((const char*)lds[0] + off);
      alo[mf] = *(const bf16x8*)((const char*)lds[1] + off);
    }
    bf16x8 bhi[2], blo[2];
    #pragma unroll
    for (int nf = 0; nf < 2; ++nf) {
      int n = nq * 32 + nf * 16 + l15;
      bhi[nf] = *(const bf16x8*)(w2hi + n * 256 + kb);
      blo[nf] = *(const bf16x8*)(w2lo + n * 256 + kb);
    }
    #pragma unroll
    for (int mf = 0; mf < 2; ++mf)
      #pragma unroll
      for (int nf = 0; nf < 2; ++nf) {
        acc2[mf][nf] = __builtin_amdgcn_mfma_f32_16x16x32_bf16(ahi[mf], bhi[nf], acc2[mf][nf], 0, 0, 0);
        acc2[mf][nf] = __builtin_amdgcn_mfma_f32_16x16x32_bf16(ahi[mf], blo[nf], acc2[mf][nf], 0, 0, 0);
        acc2[mf][nf] = __builtin_amdgcn_mfma_f32_16x16x32_bf16(alo[mf], bhi[nf], acc2[mf][nf], 0, 0, 0);
      }
  }
  __syncthreads();   // done with H planes

  // ---- epilogue: +b2, store y, column sum/sumsq ----
  float* red = (float*)lds;            // 256 floats reused
  if (tid < 256) red[tid] = 0.f;
  __syncthreads();
  #pragma unroll
  for (int nf = 0; nf < 2; ++nf) {
    int col = nq * 32 + nf * 16 + l15;
    float bb = nd.b2[col];
    #pragma unroll
    for (int mf = 0; mf < 2; ++mf) {
      int rowb = m0 + mh * 32 + mf * 16 + l4 * 4;
      float s = 0.f, q = 0.f;
      #pragma unroll
      for (int r = 0; r < 4; ++r) {
        float v = acc2[mf][nf][r] + bb;
        nd.y[(size_t)(rowb + r) * 128 + col] = v;
        s += v; q += v * v;
      }
      atomicAdd(&red[col], s);
      atomicAdd(&red[128 + col], q);
    }
  }
  __syncthreads();
  if (tid < 128)      atomicAdd(&nd.sum[tid], red[tid]);
  else if (tid < 256) atomicAdd(&nd.sumsq[tid - 128], red[tid]);
}

// BN normalize (in place) + optional noise. One thread = one float4 (4 cols).
__global__ __launch_bounds__(256) void bn_apply(NodeC c0, NodeC c1) {
  const NodeC c = (blockIdx.y == 0) ? c0 : c1;
  const size_t e = (size_t)blockIdx.x * blockDim.x + threadIdx.x;  // float4 idx
  const int col4 = ((int)e & 31) * 4;
  const float invB = 1.0f / 65536.0f;

  float4 s = *(const float4*)(c.sum + col4);
  float4 q = *(const float4*)(c.sumsq + col4);
  float mu0 = s.x * invB, mu1 = s.y * invB, mu2 = s.z * invB, mu3 = s.w * invB;
  float rs0 = rsqrtf(q.x * invB - mu0 * mu0 + EPS_BN);
  float rs1 = rsqrtf(q.y * invB - mu1 * mu1 + EPS_BN);
  float rs2 = rsqrtf(q.z * invB - mu2 * mu2 + EPS_BN);
  float rs3 = rsqrtf(q.w * invB - mu3 * mu3 + EPS_BN);

  float4 g  = *(const float4*)(c.gamma + col4);
  float4 bt = *(const float4*)(c.beta + col4);
  float4 yv = *(const float4*)(c.y + e * 4);

  float4 o;
  o.x = g.x * (yv.x - mu0) * rs0 + bt.x;
  o.y = g.y * (yv.y - mu1) * rs1 + bt.y;
  o.z = g.z * (yv.z - mu2) * rs2 + bt.z;
  o.w = g.w * (yv.w - mu3) * rs3 + bt.w;
  if (c.noise) {
    float4 nz = *(const float4*)(c.noise + e * 4);
    o.x += NSTD * nz.x; o.y += NSTD * nz.y; o.z += NSTD * nz.z; o.w += NSTD * nz.w;
  }
  *(float4*)(c.out + e * 4) = o;
}

extern "C" void kernel_launch(void* const* d_in, const int* in_sizes, int n_in,
                              void* d_out, int out_size, void* d_ws, size_t ws_size,
                              hipStream_t stream) {
  const float* x1    = (const float*)d_in[0];
  const float* x2    = (const float*)d_in[1];
  const float* W1    = (const float*)d_in[2];
  const float* b1    = (const float*)d_in[3];
  const float* W2    = (const float*)d_in[4];
  const float* b2    = (const float*)d_in[5];
  const float* gamma = (const float*)d_in[6];
  const float* beta  = (const float*)d_in[7];
  const float* noise = (const float*)d_in[8];
  float* out = (float*)d_out;

  const size_t S = (size_t)BROWS * 128;
  float* o3 = out;
  float* o4 = out + S;
  float* o0 = out + 2 * S;
  float* o1 = out + 3 * S;
  float* o2 = out + 4 * S;

  float* stats = (float*)d_ws;                       // 5 x (sum[128], sumsq[128])
  short* wbuf  = (short*)((char*)d_ws + WOFF);       // split-transposed weights

  auto mkA = [&](int i, const float* pA, int ldA, const float* pB, int ldB, float* y) {
    NodeA n;
    n.inA = pA; n.inB = pB; n.ldA = ldA; n.ldB = ldB;
    n.w1t = wbuf + (size_t)i * WNODE;
    n.w2t = wbuf + (size_t)i * WNODE + 131072;
    n.b1 = b1 + (size_t)i * 256;
    n.b2 = b2 + (size_t)i * 128;
    n.y = y;
    n.sum = stats + i * 256;
    n.sumsq = stats + i * 256 + 128;
    return n;
  };
  auto mkC = [&](int i, float* y, const float* nz) {
    NodeC c;
    c.y = y; c.out = y;
    c.sum = stats + i * 256;
    c.sumsq = stats + i * 256 + 128;
    c.gamma = gamma + (size_t)i * 128;
    c.beta  = beta + (size_t)i * 128;
    c.noise = nz;
    return c;
  };

  // prep: zero stats, build split-bf16 transposed weights in ws
  zero_f32<<<dim3(5), dim3(256), 0, stream>>>(stats, 5 * 256);
  prep_weights<<<dim3(240), dim3(256), 0, stream>>>(W1, W2, wbuf);

  dim3 blkM(512), blkB(256);

  // nodes 0,1 (inputs x1,x2)
  NodeA a0 = mkA(0, x1, 256, x1 + 128, 256, o0);
  NodeA a1 = mkA(1, x2, 256, x2 + 128, 256, o1);
  mlp_node<<<dim3(BROWS / 64, 2), blkM, 0, stream>>>(a0, a1);
  NodeC c0 = mkC(0, o0, nullptr);
  NodeC c1 = mkC(1, o1, nullptr);
  bn_apply<<<dim3(S / 4 / 256, 2), blkB, 0, stream>>>(c0, c1);

  // node 2 (concat(o0,o1)) + noise[0]
  NodeA a2 = mkA(2, o0, 128, o1, 128, o2);
  mlp_node<<<dim3(BROWS / 64, 1), blkM, 0, stream>>>(a2, a2);
  NodeC c2 = mkC(2, o2, noise);
  bn_apply<<<dim3(S / 4 / 256, 1), blkB, 0, stream>>>(c2, c2);

  // nodes 3 (concat(o0,o2)), 4 (concat(o1,o2))
  NodeA a3 = mkA(3, o0, 128, o2, 128, o3);
  NodeA a4 = mkA(4, o1, 128, o2, 128, o4);
  mlp_node<<<dim3(BROWS / 64, 2), blkM, 0, stream>>>(a3, a4);
  NodeC c3 = mkC(3, o3, noise + S);
  NodeC c4 = mkC(4, o4, noise + 2 * S);
  bn_apply<<<dim3(S / 4 / 256, 2), blkB, 0, stream>>>(c3, c4);
}

// Round 6
// 645.422 us; speedup vs baseline: 2.4238x; 1.4938x over previous
//
#include <hip/hip_runtime.h>

typedef short bf16x8 __attribute__((ext_vector_type(8)));
typedef float f32x4 __attribute__((ext_vector_type(4)));

#define BROWS 65536
#define EPS_BN 1e-5f
#define NSTD 0.1f

// ws layout: [0, 5120)            : 5 nodes x (sum[128], sumsq[128]) fp32 stats
//            [8192, 8192+1.97MB)  : split-bf16 FRAGMENT-MAJOR tiled weights, per node:
//   W1 hi: [kt(8)][ntile(16)][lane(64)][8]  (65536 shorts), W1 lo at +65536
//   W2 hi: [kt(8)][ntile(8)][lane(64)][8]   (32768 shorts) at +131072, W2 lo at +32768 from there
// Tile semantics: n = ntile*16 + (lane&15), k = kt*32 + (lane>>4)*8 + j  -> exactly the
// MFMA B-fragment each lane needs, so a wave's load is base + lane*16B = 1KB coalesced.
#define WNODE 196608   // shorts per node
#define WOFF  8192     // byte offset of weights in ws

__device__ __forceinline__ void split1(float x, short& hi, short& lo) {
  unsigned u = __float_as_uint(x);
  hi = (short)(u >> 16);
  float hf = __uint_as_float(u & 0xffff0000u);
  float l = x - hf;
  lo = (short)(__float_as_uint(l) >> 16);
}

__global__ void zero_f32(float* p, int n) {
  int i = blockIdx.x * blockDim.x + threadIdx.x;
  if (i < n) p[i] = 0.0f;
}

// Transpose + split weights into fragment-major tiles (see header comment).
__global__ __launch_bounds__(256) void prep_weights(const float* W1, const float* W2, short* wbuf) {
  int u = blockIdx.x * 256 + threadIdx.x;   // 61440 units, 8 k-elems each
  if (u >= 61440) return;
  if (u < 40960) {                           // W1: 5 nodes x 8 kt x 16 ntile x 64 lanes
    int node = u >> 13;
    int r = u & 8191;
    int kt = r >> 10;
    int r2 = r & 1023;
    int ntile = r2 >> 6;
    int ln = r2 & 63;
    int n = ntile * 16 + (ln & 15);
    int k0 = kt * 32 + (ln >> 4) * 8;
    const float* src = W1 + (size_t)node * 65536 + (size_t)k0 * 256 + n;
    short* dsthi = wbuf + (size_t)node * WNODE + kt * 8192 + ntile * 512 + ln * 8;
    bf16x8 h8, l8;
    #pragma unroll
    for (int j = 0; j < 8; ++j) { short hh, ll; split1(src[j * 256], hh, ll); h8[j] = hh; l8[j] = ll; }
    *(bf16x8*)dsthi = h8;
    *(bf16x8*)(dsthi + 65536) = l8;
  } else {                                   // W2: 5 nodes x 8 kt x 8 ntile x 64 lanes
    int u2 = u - 40960;
    int node = u2 >> 12;
    int r = u2 & 4095;
    int kt = r >> 9;
    int r2 = r & 511;
    int ntile = r2 >> 6;
    int ln = r2 & 63;
    int n = ntile * 16 + (ln & 15);
    int k0 = kt * 32 + (ln >> 4) * 8;
    const float* src = W2 + (size_t)node * 32768 + (size_t)k0 * 128 + n;
    short* dsthi = wbuf + (size_t)node * WNODE + 131072 + kt * 4096 + ntile * 512 + ln * 8;
    bf16x8 h8, l8;
    #pragma unroll
    for (int j = 0; j < 8; ++j) { short hh, ll; split1(src[j * 128], hh, ll); h8[j] = hh; l8[j] = ll; }
    *(bf16x8*)dsthi = h8;
    *(bf16x8*)(dsthi + 32768) = l8;
  }
}

struct NodeA {
  const float* inA;   // cols 0..127, row stride ldA
  const float* inB;   // cols 128..255, row stride ldB
  int ldA, ldB;
  const short* w1t;   // tiled, hi at 0, lo at +65536 shorts
  const short* w2t;   // tiled, hi at 0, lo at +32768 shorts
  const float* b1; const float* b2;
  float* y; float* sum; float* sumsq;
};

struct NodeC {
  const float* y; float* out;
  const float* sum; const float* sumsq;
  const float* gamma; const float* beta;
  const float* noise;
};

// Fused split-bf16 MFMA node: y = relu(x@W1+b1)@W2 + b2, + column sum/sumsq.
// 512 threads (8 waves), tile 64 rows. Wave grid: 2(M) x 4(N).
__global__ __launch_bounds__(512) void mlp_node(NodeA nd0, NodeA nd1) {
  const NodeA nd = (blockIdx.y == 0) ? nd0 : nd1;
  __shared__ short lds[2][64 * 256];   // hi/lo planes, XOR-swizzled rows (64 KB)

  const int tid = threadIdx.x;
  const int lane = tid & 63;
  const int wid = tid >> 6;
  const int l15 = lane & 15;
  const int l4 = lane >> 4;            // 0..3
  const int m0 = blockIdx.x * 64;
  const int mh = wid >> 2;             // 0..1 : 32-row half
  const int nq = wid & 3;              // 0..3

  // ---- stage X (64x256 fp32) -> split bf16 hi/lo planes in LDS ----
  #pragma unroll
  for (int it = 0; it < 4; ++it) {
    int u = tid + it * 512;            // 2048 units of 8 elems
    int row = u >> 5, kc = u & 31;
    const float* src = (kc < 16) ? (nd.inA + (size_t)(m0 + row) * nd.ldA + kc * 8)
                                 : (nd.inB + (size_t)(m0 + row) * nd.ldB + (kc - 16) * 8);
    float4 a = *(const float4*)src;
    float4 b = *(const float4*)(src + 4);
    bf16x8 h8, l8;
    #pragma unroll
    for (int j = 0; j < 8; ++j) {
      float f = (j < 4) ? (&a.x)[j] : (&b.x)[j - 4];
      short hh, ll; split1(f, hh, ll);
      h8[j] = hh; l8[j] = ll;
    }
    int off = row * 512 + ((kc * 16) ^ ((row & 7) << 4));
    *(bf16x8*)((char*)lds[0] + off) = h8;
    *(bf16x8*)((char*)lds[1] + off) = l8;
  }
  __syncthreads();

  // ---- GEMM1: H(64x256) = X @ W1  (3-product split-bf16) ----
  f32x4 acc[2][4] = {};
  const short* __restrict__ w1hi = nd.w1t;
  const short* __restrict__ w1lo = nd.w1t + 65536;
  for (int kt = 0; kt < 8; ++kt) {
    int kb = kt * 32 + l4 * 8;
    bf16x8 ahi[2], alo[2];
    #pragma unroll
    for (int mf = 0; mf < 2; ++mf) {
      int row = mh * 32 + mf * 16 + l15;
      int off = row * 512 + ((kb * 2) ^ ((row & 7) << 4));
      ahi[mf] = *(const bf16x8*)((const char*)lds[0] + off);
      alo[mf] = *(const bf16x8*)((const char*)lds[1] + off);
    }
    bf16x8 bhi[4], blo[4];
    #pragma unroll
    for (int nf = 0; nf < 4; ++nf) {
      int tb = kt * 8192 + (nq * 4 + nf) * 512 + lane * 8;   // fragment-major tile
      bhi[nf] = *(const bf16x8*)(w1hi + tb);
      blo[nf] = *(const bf16x8*)(w1lo + tb);
    }
    #pragma unroll
    for (int mf = 0; mf < 2; ++mf)
      #pragma unroll
      for (int nf = 0; nf < 4; ++nf) {
        acc[mf][nf] = __builtin_amdgcn_mfma_f32_16x16x32_bf16(ahi[mf], bhi[nf], acc[mf][nf], 0, 0, 0);
        acc[mf][nf] = __builtin_amdgcn_mfma_f32_16x16x32_bf16(ahi[mf], blo[nf], acc[mf][nf], 0, 0, 0);
        acc[mf][nf] = __builtin_amdgcn_mfma_f32_16x16x32_bf16(alo[mf], bhi[nf], acc[mf][nf], 0, 0, 0);
      }
  }
  __syncthreads();   // all waves done reading X planes

  // ---- bias + relu + split -> H planes (overwrite X planes) ----
  #pragma unroll
  for (int nf = 0; nf < 4; ++nf) {
    int col = nq * 64 + nf * 16 + l15;
    float bb = nd.b1[col];
    #pragma unroll
    for (int mf = 0; mf < 2; ++mf) {
      int rowb = mh * 32 + mf * 16 + l4 * 4;
      #pragma unroll
      for (int r = 0; r < 4; ++r) {
        float h = fmaxf(acc[mf][nf][r] + bb, 0.f);
        short hh, ll; split1(h, hh, ll);
        int off = (rowb + r) * 512 + ((col * 2) ^ (((rowb + r) & 7) << 4));
        *(short*)((char*)lds[0] + off) = hh;
        *(short*)((char*)lds[1] + off) = ll;
      }
    }
  }
  __syncthreads();

  // ---- GEMM2: Y(64x128) = H @ W2 ----
  f32x4 acc2[2][2] = {};
  const short* __restrict__ w2hi = nd.w2t;
  const short* __restrict__ w2lo = nd.w2t + 32768;
  for (int kt = 0; kt < 8; ++kt) {
    int kb = kt * 32 + l4 * 8;
    bf16x8 ahi[2], alo[2];
    #pragma unroll
    for (int mf = 0; mf < 2; ++mf) {
      int row = mh * 32 + mf * 16 + l15;
      int off = row * 512 + ((kb * 2) ^ ((row & 7) << 4));
      ahi[mf] = *(const bf16x8*)((const char*)lds[0] + off);
      alo[mf] = *(const bf16x8*)((const char*)lds[1] + off);
    }
    bf16x8 bhi[2], blo[2];
    #pragma unroll
    for (int nf = 0; nf < 2; ++nf) {
      int tb = kt * 4096 + (nq * 2 + nf) * 512 + lane * 8;   // fragment-major tile
      bhi[nf] = *(const bf16x8*)(w2hi + tb);
      blo[nf] = *(const bf16x8*)(w2lo + tb);
    }
    #pragma unroll
    for (int mf = 0; mf < 2; ++mf)
      #pragma unroll
      for (int nf = 0; nf < 2; ++nf) {
        acc2[mf][nf] = __builtin_amdgcn_mfma_f32_16x16x32_bf16(ahi[mf], bhi[nf], acc2[mf][nf], 0, 0, 0);
        acc2[mf][nf] = __builtin_amdgcn_mfma_f32_16x16x32_bf16(ahi[mf], blo[nf], acc2[mf][nf], 0, 0, 0);
        acc2[mf][nf] = __builtin_amdgcn_mfma_f32_16x16x32_bf16(alo[mf], bhi[nf], acc2[mf][nf], 0, 0, 0);
      }
  }
  __syncthreads();   // done with H planes

  // ---- epilogue: +b2, store y, column sum/sumsq ----
  float* red = (float*)lds;            // 256 floats reused
  if (tid < 256) red[tid] = 0.f;
  __syncthreads();
  #pragma unroll
  for (int nf = 0; nf < 2; ++nf) {
    int col = nq * 32 + nf * 16 + l15;
    float bb = nd.b2[col];
    #pragma unroll
    for (int mf = 0; mf < 2; ++mf) {
      int rowb = m0 + mh * 32 + mf * 16 + l4 * 4;
      float s = 0.f, q = 0.f;
      #pragma unroll
      for (int r = 0; r < 4; ++r) {
        float v = acc2[mf][nf][r] + bb;
        nd.y[(size_t)(rowb + r) * 128 + col] = v;
        s += v; q += v * v;
      }
      atomicAdd(&red[col], s);
      atomicAdd(&red[128 + col], q);
    }
  }
  __syncthreads();
  if (tid < 128)      atomicAdd(&nd.sum[tid], red[tid]);
  else if (tid < 256) atomicAdd(&nd.sumsq[tid - 128], red[tid]);
}

// BN normalize (in place) + optional noise. One thread = one float4 (4 cols).
__global__ __launch_bounds__(256) void bn_apply(NodeC c0, NodeC c1) {
  const NodeC c = (blockIdx.y == 0) ? c0 : c1;
  const size_t e = (size_t)blockIdx.x * blockDim.x + threadIdx.x;  // float4 idx
  const int col4 = ((int)e & 31) * 4;
  const float invB = 1.0f / 65536.0f;

  float4 s = *(const float4*)(c.sum + col4);
  float4 q = *(const float4*)(c.sumsq + col4);
  float mu0 = s.x * invB, mu1 = s.y * invB, mu2 = s.z * invB, mu3 = s.w * invB;
  float rs0 = rsqrtf(q.x * invB - mu0 * mu0 + EPS_BN);
  float rs1 = rsqrtf(q.y * invB - mu1 * mu1 + EPS_BN);
  float rs2 = rsqrtf(q.z * invB - mu2 * mu2 + EPS_BN);
  float rs3 = rsqrtf(q.w * invB - mu3 * mu3 + EPS_BN);

  float4 g  = *(const float4*)(c.gamma + col4);
  float4 bt = *(const float4*)(c.beta + col4);
  float4 yv = *(const float4*)(c.y + e * 4);

  float4 o;
  o.x = g.x * (yv.x - mu0) * rs0 + bt.x;
  o.y = g.y * (yv.y - mu1) * rs1 + bt.y;
  o.z = g.z * (yv.z - mu2) * rs2 + bt.z;
  o.w = g.w * (yv.w - mu3) * rs3 + bt.w;
  if (c.noise) {
    float4 nz = *(const float4*)(c.noise + e * 4);
    o.x += NSTD * nz.x; o.y += NSTD * nz.y; o.z += NSTD * nz.z; o.w += NSTD * nz.w;
  }
  *(float4*)(c.out + e * 4) = o;
}

extern "C" void kernel_launch(void* const* d_in, const int* in_sizes, int n_in,
                              void* d_out, int out_size, void* d_ws, size_t ws_size,
                              hipStream_t stream) {
  const float* x1    = (const float*)d_in[0];
  const float* x2    = (const float*)d_in[1];
  const float* W1    = (const float*)d_in[2];
  const float* b1    = (const float*)d_in[3];
  const float* W2    = (const float*)d_in[4];
  const float* b2    = (const float*)d_in[5];
  const float* gamma = (const float*)d_in[6];
  const float* beta  = (const float*)d_in[7];
  const float* noise = (const float*)d_in[8];
  float* out = (float*)d_out;

  const size_t S = (size_t)BROWS * 128;
  float* o3 = out;
  float* o4 = out + S;
  float* o0 = out + 2 * S;
  float* o1 = out + 3 * S;
  float* o2 = out + 4 * S;

  float* stats = (float*)d_ws;                       // 5 x (sum[128], sumsq[128])
  short* wbuf  = (short*)((char*)d_ws + WOFF);       // split, fragment-major weights

  auto mkA = [&](int i, const float* pA, int ldA, const float* pB, int ldB, float* y) {
    NodeA n;
    n.inA = pA; n.inB = pB; n.ldA = ldA; n.ldB = ldB;
    n.w1t = wbuf + (size_t)i * WNODE;
    n.w2t = wbuf + (size_t)i * WNODE + 131072;
    n.b1 = b1 + (size_t)i * 256;
    n.b2 = b2 + (size_t)i * 128;
    n.y = y;
    n.sum = stats + i * 256;
    n.sumsq = stats + i * 256 + 128;
    return n;
  };
  auto mkC = [&](int i, float* y, const float* nz) {
    NodeC c;
    c.y = y; c.out = y;
    c.sum = stats + i * 256;
    c.sumsq = stats + i * 256 + 128;
    c.gamma = gamma + (size_t)i * 128;
    c.beta  = beta + (size_t)i * 128;
    c.noise = nz;
    return c;
  };

  // prep: zero stats, build split-bf16 tiled weights in ws
  zero_f32<<<dim3(5), dim3(256), 0, stream>>>(stats, 5 * 256);
  prep_weights<<<dim3(240), dim3(256), 0, stream>>>(W1, W2, wbuf);

  dim3 blkM(512), blkB(256);

  // nodes 0,1 (inputs x1,x2)
  NodeA a0 = mkA(0, x1, 256, x1 + 128, 256, o0);
  NodeA a1 = mkA(1, x2, 256, x2 + 128, 256, o1);
  mlp_node<<<dim3(BROWS / 64, 2), blkM, 0, stream>>>(a0, a1);
  NodeC c0 = mkC(0, o0, nullptr);
  NodeC c1 = mkC(1, o1, nullptr);
  bn_apply<<<dim3(S / 4 / 256, 2), blkB, 0, stream>>>(c0, c1);

  // node 2 (concat(o0,o1)) + noise[0]
  NodeA a2 = mkA(2, o0, 128, o1, 128, o2);
  mlp_node<<<dim3(BROWS / 64, 1), blkM, 0, stream>>>(a2, a2);
  NodeC c2 = mkC(2, o2, noise);
  bn_apply<<<dim3(S / 4 / 256, 1), blkB, 0, stream>>>(c2, c2);

  // nodes 3 (concat(o0,o2)), 4 (concat(o1,o2))
  NodeA a3 = mkA(3, o0, 128, o2, 128, o3);
  NodeA a4 = mkA(4, o1, 128, o2, 128, o4);
  mlp_node<<<dim3(BROWS / 64, 2), blkM, 0, stream>>>(a3, a4);
  NodeC c3 = mkC(3, o3, noise + S);
  NodeC c4 = mkC(4, o4, noise + 2 * S);
  bn_apply<<<dim3(S / 4 / 256, 2), blkB, 0, stream>>>(c3, c4);
}